// Round 1
// baseline (586.124 us; speedup 1.0000x reference)
//
#include <hip/hip_runtime.h>
#include <math.h>

#define D_IN 256
#define NH 8
#define DOUT 32
#define NOUT 256  // NH*DOUT
#define NEG_SLOPE 0.2f

// ---------------- GEMM: C[M,256] = A[M,256] @ B[256,256], fp32 ----------------
__global__ __launch_bounds__(256) void gemm_kernel(const float* __restrict__ A,
                                                   const float* __restrict__ B,
                                                   float* __restrict__ C, int M) {
    __shared__ float As[64][20];   // [BM][BK+4 pad]
    __shared__ float Bs[16][64];   // [BK][BN]
    int tid = threadIdx.x;
    int tx = tid & 15, ty = tid >> 4;
    int row0 = blockIdx.y * 64;
    int col0 = blockIdx.x * 64;
    float acc[4][4] = {};
    for (int kb = 0; kb < D_IN; kb += 16) {
        // A tile 64x16, coalesced float4 loads
        {
            int ar = tid >> 2, ac = (tid & 3) * 4;
            float4 v = make_float4(0.f, 0.f, 0.f, 0.f);
            int grow = row0 + ar;
            if (grow < M) v = *reinterpret_cast<const float4*>(&A[(size_t)grow * D_IN + kb + ac]);
            *reinterpret_cast<float4*>(&As[ar][ac]) = v;
        }
        // B tile 16x64
        {
            int br = tid >> 4, bc = (tid & 15) * 4;
            float4 v = *reinterpret_cast<const float4*>(&B[(size_t)(kb + br) * NOUT + col0 + bc]);
            *reinterpret_cast<float4*>(&Bs[br][bc]) = v;
        }
        __syncthreads();
#pragma unroll
        for (int k4 = 0; k4 < 4; ++k4) {
            float4 a[4], b[4];
#pragma unroll
            for (int i = 0; i < 4; ++i)
                a[i] = *reinterpret_cast<const float4*>(&As[ty * 4 + i][k4 * 4]);
#pragma unroll
            for (int kk = 0; kk < 4; ++kk)
                b[kk] = *reinterpret_cast<const float4*>(&Bs[k4 * 4 + kk][tx * 4]);
#pragma unroll
            for (int kk = 0; kk < 4; ++kk) {
#pragma unroll
                for (int i = 0; i < 4; ++i) {
                    float av = (kk == 0) ? a[i].x : (kk == 1) ? a[i].y : (kk == 2) ? a[i].z : a[i].w;
                    acc[i][0] += av * b[kk].x;
                    acc[i][1] += av * b[kk].y;
                    acc[i][2] += av * b[kk].z;
                    acc[i][3] += av * b[kk].w;
                }
            }
        }
        __syncthreads();
    }
#pragma unroll
    for (int i = 0; i < 4; ++i) {
        int grow = row0 + ty * 4 + i;
        if (grow < M) {
            float4 v = make_float4(acc[i][0], acc[i][1], acc[i][2], acc[i][3]);
            *reinterpret_cast<float4*>(&C[(size_t)grow * NOUT + col0 + tx * 4]) = v;
        }
    }
}

// ---------------- el/er: per-node attention logits ----------------
__global__ __launch_bounds__(256) void elr_kernel(const float* __restrict__ proj,
                                                  const float* __restrict__ al,
                                                  const float* __restrict__ ar,
                                                  float* __restrict__ el,
                                                  float* __restrict__ er, int N) {
    int n = blockIdx.x;
    int t = threadIdx.x;
    float p = proj[(size_t)n * NOUT + t];
    float l = p * al[t];
    float r = p * ar[t];
#pragma unroll
    for (int s = 16; s; s >>= 1) {
        l += __shfl_xor(l, s, 32);
        r += __shfl_xor(r, s, 32);
    }
    if ((t & 31) == 0) {
        int h = t >> 5;
        el[n * NH + h] = l;
        er[n * NH + h] = r;
    }
}

// ---------------- degree histogram ----------------
__global__ void hist_kernel(const int* __restrict__ dst, int* __restrict__ deg, int E) {
    int i = blockIdx.x * blockDim.x + threadIdx.x;
    if (i < E) atomicAdd(&deg[dst[i]], 1);
}

// ---------------- single-block exclusive scan (N up to ~1e6) ----------------
__global__ __launch_bounds__(1024) void scan_kernel(const int* __restrict__ deg,
                                                    int* __restrict__ off,
                                                    int* __restrict__ cur, int N) {
    __shared__ int tmp[1024];
    __shared__ int carry_s;
    int t = threadIdx.x;
    if (t == 0) carry_s = 0;
    __syncthreads();
    for (int base = 0; base < N; base += 1024) {
        int i = base + t;
        int v = (i < N) ? deg[i] : 0;
        tmp[t] = v;
        __syncthreads();
        for (int s = 1; s < 1024; s <<= 1) {
            int add = (t >= s) ? tmp[t - s] : 0;
            __syncthreads();
            tmp[t] += add;
            __syncthreads();
        }
        int excl = tmp[t] - v + carry_s;
        if (i < N) { off[i] = excl; cur[i] = excl; }
        __syncthreads();
        if (t == 1023) carry_s += tmp[1023];
        __syncthreads();
    }
}

// ---------------- scatter edge ids into CSR ----------------
__global__ void scatter_kernel(const int* __restrict__ dst, int* __restrict__ cur,
                               int* __restrict__ csr, int E) {
    int i = blockIdx.x * blockDim.x + threadIdx.x;
    if (i < E) {
        int p = atomicAdd(&cur[dst[i]], 1);
        csr[p] = i;
    }
}

// ---------------- fused edge-softmax + aggregation, one block per dst ----------------
__global__ __launch_bounds__(256) void agg_kernel(const float* __restrict__ proj,
                                                  const float* __restrict__ el,
                                                  const float* __restrict__ er,
                                                  const int* __restrict__ src,
                                                  const int* __restrict__ csr,
                                                  const int* __restrict__ off,
                                                  const int* __restrict__ deg,
                                                  float* __restrict__ out) {
    int v = blockIdx.x;
    int t = threadIdx.x;
    int h = t >> 5, lane = t & 31;
    int base = off[v];
    int n = deg[v];
    float erv = er[v * NH + h];

    // phase 1: per-head max over incoming edges (32 lanes stride edges)
    float m = -INFINITY;
    for (int k = lane; k < n; k += 32) {
        int u = src[csr[base + k]];
        float x = el[u * NH + h] + erv;
        x = (x > 0.f) ? x : NEG_SLOPE * x;
        m = fmaxf(m, x);
    }
#pragma unroll
    for (int s = 16; s; s >>= 1) m = fmaxf(m, __shfl_xor(m, s, 32));

    // phase 2: per-head sum of exp
    float ssum = 0.f;
    for (int k = lane; k < n; k += 32) {
        int u = src[csr[base + k]];
        float x = el[u * NH + h] + erv;
        x = (x > 0.f) ? x : NEG_SLOPE * x;
        ssum += __expf(x - m);
    }
#pragma unroll
    for (int s = 16; s; s >>= 1) ssum += __shfl_xor(ssum, s, 32);
    float inv = (n > 0) ? 1.f / ssum : 0.f;

    // phase 3: weighted gather; thread t owns feature t = h*32 + d
    float acc = 0.f;
    for (int k = 0; k < n; ++k) {
        int u = src[csr[base + k]];
        float x = el[u * NH + h] + erv;
        x = (x > 0.f) ? x : NEG_SLOPE * x;
        float p = __expf(x - m) * inv;
        acc += p * proj[(size_t)u * NOUT + t];
    }
    out[(size_t)v * NOUT + t] = acc;
}

extern "C" void kernel_launch(void* const* d_in, const int* in_sizes, int n_in,
                              void* d_out, int out_size, void* d_ws, size_t ws_size,
                              hipStream_t stream) {
    const float* feat   = (const float*)d_in[0];
    const float* W      = (const float*)d_in[1];
    const float* attn_l = (const float*)d_in[2];
    const float* attn_r = (const float*)d_in[3];
    const int*   src    = (const int*)d_in[4];
    const int*   dst    = (const int*)d_in[5];
    float* out = (float*)d_out;

    const int M = in_sizes[0] / D_IN;   // 50000
    const int E = in_sizes[4];          // 800000

    char* ws = (char*)d_ws;
    size_t off_proj = 0;
    size_t off_el   = off_proj + (size_t)M * NOUT * 4;
    size_t off_er   = off_el   + (size_t)M * NH * 4;
    size_t off_deg  = off_er   + (size_t)M * NH * 4;
    size_t off_ofs  = off_deg  + (size_t)M * 4;
    size_t off_cur  = off_ofs  + (size_t)M * 4;
    size_t off_csr  = off_cur  + (size_t)M * 4;

    float* proj = (float*)(ws + off_proj);
    float* el   = (float*)(ws + off_el);
    float* er   = (float*)(ws + off_er);
    int*   deg  = (int*)(ws + off_deg);
    int*   ofs  = (int*)(ws + off_ofs);
    int*   cur  = (int*)(ws + off_cur);
    int*   csr  = (int*)(ws + off_csr);

    // zero degree counters
    hipMemsetAsync(deg, 0, (size_t)M * 4, stream);

    // 1. projection GEMM
    dim3 ggrid(NOUT / 64, (M + 63) / 64);
    gemm_kernel<<<ggrid, 256, 0, stream>>>(feat, W, proj, M);

    // 2. el / er logits
    elr_kernel<<<M, 256, 0, stream>>>(proj, attn_l, attn_r, el, er, M);

    // 3. CSR build
    int eblocks = (E + 255) / 256;
    hist_kernel<<<eblocks, 256, 0, stream>>>(dst, deg, E);
    scan_kernel<<<1, 1024, 0, stream>>>(deg, ofs, cur, M);
    scatter_kernel<<<eblocks, 256, 0, stream>>>(dst, cur, csr, E);

    // 4. fused softmax + aggregation
    agg_kernel<<<M, 256, 0, stream>>>(proj, el, er, src, csr, ofs, deg, out);
}

// Round 2
// 494.373 us; speedup vs baseline: 1.1856x; 1.1856x over previous
//
#include <hip/hip_runtime.h>
#include <math.h>

#define D_IN 256
#define NH 8
#define DOUT 32
#define NOUT 256  // NH*DOUT
#define NEG_SLOPE 0.2f

// ---------------- GEMM: C[M,256] = A[M,256] @ B[256,256], fp32 ----------------
// 128x128 tile, BK=16, 256 threads, 8x8 per thread (split 4+4 offsets for
// conflict-free float4 LDS reads).
__global__ __launch_bounds__(256) void gemm_kernel(const float* __restrict__ A,
                                                   const float* __restrict__ B,
                                                   float* __restrict__ C, int M) {
    __shared__ float As[16][128];  // k-major
    __shared__ float Bs[16][128];
    int tid = threadIdx.x;
    int tx = tid & 15;   // col group
    int ty = tid >> 4;   // row group
    int row0 = blockIdx.y * 128;
    int col0 = blockIdx.x * 128;
    float acc[8][8] = {};

    for (int kb = 0; kb < D_IN; kb += 16) {
        // A tile: 128 rows x 16 k. thread: row ar & ar+64, k = ac..ac+3
        int ar = tid >> 2;
        int ac = (tid & 3) * 4;
        float4 a0 = make_float4(0.f, 0.f, 0.f, 0.f), a1 = a0;
        int r0 = row0 + ar, r1 = row0 + ar + 64;
        if (r0 < M) a0 = *reinterpret_cast<const float4*>(&A[(size_t)r0 * D_IN + kb + ac]);
        if (r1 < M) a1 = *reinterpret_cast<const float4*>(&A[(size_t)r1 * D_IN + kb + ac]);
        As[ac + 0][ar] = a0.x; As[ac + 1][ar] = a0.y; As[ac + 2][ar] = a0.z; As[ac + 3][ar] = a0.w;
        As[ac + 0][ar + 64] = a1.x; As[ac + 1][ar + 64] = a1.y; As[ac + 2][ar + 64] = a1.z; As[ac + 3][ar + 64] = a1.w;
        // B tile: 16 k x 128 cols
        int br = tid >> 4;
        int bc = (tid & 15) * 4;
        float4 b0 = *reinterpret_cast<const float4*>(&B[(size_t)(kb + br) * NOUT + col0 + bc]);
        float4 b1 = *reinterpret_cast<const float4*>(&B[(size_t)(kb + br) * NOUT + col0 + bc + 64]);
        *reinterpret_cast<float4*>(&Bs[br][bc]) = b0;
        *reinterpret_cast<float4*>(&Bs[br][bc + 64]) = b1;
        __syncthreads();
#pragma unroll
        for (int k = 0; k < 16; ++k) {
            float4 a0f = *reinterpret_cast<const float4*>(&As[k][ty * 4]);
            float4 a1f = *reinterpret_cast<const float4*>(&As[k][ty * 4 + 64]);
            float4 b0f = *reinterpret_cast<const float4*>(&Bs[k][tx * 4]);
            float4 b1f = *reinterpret_cast<const float4*>(&Bs[k][tx * 4 + 64]);
            float av[8] = {a0f.x, a0f.y, a0f.z, a0f.w, a1f.x, a1f.y, a1f.z, a1f.w};
            float bv[8] = {b0f.x, b0f.y, b0f.z, b0f.w, b1f.x, b1f.y, b1f.z, b1f.w};
#pragma unroll
            for (int i = 0; i < 8; ++i)
#pragma unroll
                for (int j = 0; j < 8; ++j) acc[i][j] += av[i] * bv[j];
        }
        __syncthreads();
    }
#pragma unroll
    for (int i = 0; i < 8; ++i) {
        int row = row0 + (i < 4 ? ty * 4 + i : 64 + ty * 4 + (i - 4));
        if (row < M) {
            float4 c0 = make_float4(acc[i][0], acc[i][1], acc[i][2], acc[i][3]);
            float4 c1 = make_float4(acc[i][4], acc[i][5], acc[i][6], acc[i][7]);
            *reinterpret_cast<float4*>(&C[(size_t)row * NOUT + col0 + tx * 4]) = c0;
            *reinterpret_cast<float4*>(&C[(size_t)row * NOUT + col0 + tx * 4 + 64]) = c1;
        }
    }
}

// ---------------- el/er: per-node attention logits ----------------
__global__ __launch_bounds__(256) void elr_kernel(const float* __restrict__ proj,
                                                  const float* __restrict__ al,
                                                  const float* __restrict__ ar,
                                                  float* __restrict__ el,
                                                  float* __restrict__ er, int N) {
    int n = blockIdx.x;
    int t = threadIdx.x;
    float p = proj[(size_t)n * NOUT + t];
    float l = p * al[t];
    float r = p * ar[t];
#pragma unroll
    for (int s = 16; s; s >>= 1) {
        l += __shfl_xor(l, s, 32);
        r += __shfl_xor(r, s, 32);
    }
    if ((t & 31) == 0) {
        int h = t >> 5;
        el[n * NH + h] = l;
        er[n * NH + h] = r;
    }
}

// ---------------- degree histogram ----------------
__global__ void hist_kernel(const int* __restrict__ dst, int* __restrict__ deg, int E) {
    int i = blockIdx.x * blockDim.x + threadIdx.x;
    if (i < E) atomicAdd(&deg[dst[i]], 1);
}

// ---------------- two-level scan ----------------
__global__ __launch_bounds__(256) void scan1_kernel(const int* __restrict__ deg,
                                                    int* __restrict__ off,
                                                    int* __restrict__ bsum, int N) {
    __shared__ int wls[4];
    int tid = threadIdx.x, lane = tid & 63, w = tid >> 6;
    int i = blockIdx.x * 256 + tid;
    int v = (i < N) ? deg[i] : 0;
    int s = v;
#pragma unroll
    for (int d = 1; d < 64; d <<= 1) {
        int t = __shfl_up(s, d, 64);
        if (lane >= d) s += t;
    }
    if (lane == 63) wls[w] = s;
    __syncthreads();
    int add = 0;
    for (int j = 0; j < w; ++j) add += wls[j];
    if (i < N) off[i] = s - v + add;
    if (tid == 255) bsum[blockIdx.x] = add + s;
}

__global__ __launch_bounds__(256) void scan2_kernel(int* __restrict__ bsum, int nb) {
    __shared__ int wls[4];
    __shared__ int carry;
    int tid = threadIdx.x, lane = tid & 63, w = tid >> 6;
    if (tid == 0) carry = 0;
    __syncthreads();
    for (int base = 0; base < nb; base += 256) {
        int i = base + tid;
        int v = (i < nb) ? bsum[i] : 0;
        int s = v;
#pragma unroll
        for (int d = 1; d < 64; d <<= 1) {
            int t = __shfl_up(s, d, 64);
            if (lane >= d) s += t;
        }
        if (lane == 63) wls[w] = s;
        __syncthreads();
        int add = carry;
        for (int j = 0; j < w; ++j) add += wls[j];
        int excl = s - v + add;
        int total = wls[0] + wls[1] + wls[2] + wls[3];
        __syncthreads();
        if (i < nb) bsum[i] = excl;
        if (tid == 0) carry += total;
        __syncthreads();
    }
}

__global__ __launch_bounds__(256) void scan3_kernel(int* __restrict__ off,
                                                    int* __restrict__ cur,
                                                    const int* __restrict__ bsum, int N) {
    int i = blockIdx.x * 256 + threadIdx.x;
    if (i < N) {
        int o = off[i] + bsum[blockIdx.x];
        off[i] = o;
        cur[i] = o;
    }
}

// ---------------- scatter SRC ids into CSR (no edge-id indirection) ----------------
__global__ void scatter_kernel(const int* __restrict__ src, const int* __restrict__ dst,
                               int* __restrict__ cur, int* __restrict__ csr, int E) {
    int i = blockIdx.x * blockDim.x + threadIdx.x;
    if (i < E) {
        int p = atomicAdd(&cur[dst[i]], 1);
        csr[p] = src[i];
    }
}

// ---------------- fused edge-softmax + aggregation, one block per dst ----------------
// 256 threads = 4 waves. Pass A: parallel max (all heads). Pass B: parallel
// exp-sum. Pass C: stage (u, p[h]) chunks in LDS, then wave-per-edge float4
// row gather, cross-wave LDS reduce.
__global__ __launch_bounds__(256) void agg_kernel(const float* __restrict__ proj,
                                                  const float* __restrict__ el,
                                                  const float* __restrict__ er,
                                                  const int* __restrict__ csrU,
                                                  const int* __restrict__ off,
                                                  const int* __restrict__ deg,
                                                  float* __restrict__ out) {
    int v = blockIdx.x;
    int tid = threadIdx.x;
    int lane = tid & 63, w = tid >> 6;

    __shared__ float erS[NH], mS[NH], invS[NH];
    __shared__ float wred[4][NH];
    __shared__ int u_s[64];
    __shared__ float p_s[64][NH + 1];
    __shared__ float accS[4][NOUT];

    int base = off[v];
    int n = deg[v];
    if (n == 0) {
        out[(size_t)v * NOUT + tid] = 0.f;
        return;
    }
    if (tid < NH) erS[tid] = er[v * NH + tid];
    __syncthreads();
    float er_r[NH];
#pragma unroll
    for (int h = 0; h < NH; ++h) er_r[h] = erS[h];

    const float4* el4 = reinterpret_cast<const float4*>(el);

    // ---- pass A: max over edges, all heads ----
    float mx[NH];
#pragma unroll
    for (int h = 0; h < NH; ++h) mx[h] = -INFINITY;
    for (int k = tid; k < n; k += 256) {
        int u = csrU[base + k];
        float4 e0 = el4[(size_t)u * 2];
        float4 e1 = el4[(size_t)u * 2 + 1];
        float x[NH] = {e0.x, e0.y, e0.z, e0.w, e1.x, e1.y, e1.z, e1.w};
#pragma unroll
        for (int h = 0; h < NH; ++h) {
            float xv = x[h] + er_r[h];
            xv = (xv > 0.f) ? xv : NEG_SLOPE * xv;
            mx[h] = fmaxf(mx[h], xv);
        }
    }
#pragma unroll
    for (int s = 32; s; s >>= 1)
#pragma unroll
        for (int h = 0; h < NH; ++h) mx[h] = fmaxf(mx[h], __shfl_xor(mx[h], s, 64));
    if (lane == 0)
#pragma unroll
        for (int h = 0; h < NH; ++h) wred[w][h] = mx[h];
    __syncthreads();
    if (tid < NH)
        mS[tid] = fmaxf(fmaxf(wred[0][tid], wred[1][tid]), fmaxf(wred[2][tid], wred[3][tid]));
    __syncthreads();
    float m_r[NH];
#pragma unroll
    for (int h = 0; h < NH; ++h) m_r[h] = mS[h];

    // ---- pass B: sum of exp ----
    float sm[NH] = {};
    for (int k = tid; k < n; k += 256) {
        int u = csrU[base + k];
        float4 e0 = el4[(size_t)u * 2];
        float4 e1 = el4[(size_t)u * 2 + 1];
        float x[NH] = {e0.x, e0.y, e0.z, e0.w, e1.x, e1.y, e1.z, e1.w};
#pragma unroll
        for (int h = 0; h < NH; ++h) {
            float xv = x[h] + er_r[h];
            xv = (xv > 0.f) ? xv : NEG_SLOPE * xv;
            sm[h] += __expf(xv - m_r[h]);
        }
    }
#pragma unroll
    for (int s = 32; s; s >>= 1)
#pragma unroll
        for (int h = 0; h < NH; ++h) sm[h] += __shfl_xor(sm[h], s, 64);
    if (lane == 0)
#pragma unroll
        for (int h = 0; h < NH; ++h) wred[w][h] = sm[h];
    __syncthreads();
    if (tid < NH) {
        float ssum = wred[0][tid] + wred[1][tid] + wred[2][tid] + wred[3][tid];
        invS[tid] = 1.f / ssum;
    }
    __syncthreads();
    float inv_r[NH];
#pragma unroll
    for (int h = 0; h < NH; ++h) inv_r[h] = invS[h];

    // ---- pass C: staged gather, one wave per edge ----
    float4 acc = make_float4(0.f, 0.f, 0.f, 0.f);
    int h4 = lane >> 3;  // head of feature lane*4
    for (int c0 = 0; c0 < n; c0 += 64) {
        int cn = min(64, n - c0);
        __syncthreads();  // protect u_s/p_s reuse
        if (tid < cn) {
            int u = csrU[base + c0 + tid];
            u_s[tid] = u;
            float4 e0 = el4[(size_t)u * 2];
            float4 e1 = el4[(size_t)u * 2 + 1];
            float x[NH] = {e0.x, e0.y, e0.z, e0.w, e1.x, e1.y, e1.z, e1.w};
#pragma unroll
            for (int h = 0; h < NH; ++h) {
                float xv = x[h] + er_r[h];
                xv = (xv > 0.f) ? xv : NEG_SLOPE * xv;
                p_s[tid][h] = __expf(xv - m_r[h]) * inv_r[h];
            }
        }
        __syncthreads();
#pragma unroll 2
        for (int k = w; k < cn; k += 4) {
            int u = u_s[k];
            float p = p_s[k][h4];
            float4 vv = *reinterpret_cast<const float4*>(&proj[(size_t)u * NOUT + lane * 4]);
            acc.x += p * vv.x;
            acc.y += p * vv.y;
            acc.z += p * vv.z;
            acc.w += p * vv.w;
        }
    }
    *reinterpret_cast<float4*>(&accS[w][lane * 4]) = acc;
    __syncthreads();
    out[(size_t)v * NOUT + tid] = accS[0][tid] + accS[1][tid] + accS[2][tid] + accS[3][tid];
}

extern "C" void kernel_launch(void* const* d_in, const int* in_sizes, int n_in,
                              void* d_out, int out_size, void* d_ws, size_t ws_size,
                              hipStream_t stream) {
    const float* feat   = (const float*)d_in[0];
    const float* W      = (const float*)d_in[1];
    const float* attn_l = (const float*)d_in[2];
    const float* attn_r = (const float*)d_in[3];
    const int*   src    = (const int*)d_in[4];
    const int*   dst    = (const int*)d_in[5];
    float* out = (float*)d_out;

    const int M = in_sizes[0] / D_IN;   // 50000
    const int E = in_sizes[4];          // 800000
    const int nb = (M + 255) / 256;

    char* ws = (char*)d_ws;
    size_t off_proj = 0;
    size_t off_el   = off_proj + (size_t)M * NOUT * 4;
    size_t off_er   = off_el   + (size_t)M * NH * 4;
    size_t off_deg  = off_er   + (size_t)M * NH * 4;
    size_t off_ofs  = off_deg  + (size_t)M * 4;
    size_t off_cur  = off_ofs  + (size_t)M * 4;
    size_t off_csr  = off_cur  + (size_t)M * 4;
    size_t off_bsum = off_csr  + (size_t)E * 4;

    float* proj = (float*)(ws + off_proj);
    float* el   = (float*)(ws + off_el);
    float* er   = (float*)(ws + off_er);
    int*   deg  = (int*)(ws + off_deg);
    int*   ofs  = (int*)(ws + off_ofs);
    int*   cur  = (int*)(ws + off_cur);
    int*   csr  = (int*)(ws + off_csr);
    int*   bsum = (int*)(ws + off_bsum);

    hipMemsetAsync(deg, 0, (size_t)M * 4, stream);

    // 1. projection GEMM
    dim3 ggrid(NOUT / 128, (M + 127) / 128);
    gemm_kernel<<<ggrid, 256, 0, stream>>>(feat, W, proj, M);

    // 2. el / er logits
    elr_kernel<<<M, 256, 0, stream>>>(proj, attn_l, attn_r, el, er, M);

    // 3. CSR build
    int eblocks = (E + 255) / 256;
    hist_kernel<<<eblocks, 256, 0, stream>>>(dst, deg, E);
    scan1_kernel<<<nb, 256, 0, stream>>>(deg, ofs, bsum, M);
    scan2_kernel<<<1, 256, 0, stream>>>(bsum, nb);
    scan3_kernel<<<nb, 256, 0, stream>>>(ofs, cur, bsum, M);
    scatter_kernel<<<eblocks, 256, 0, stream>>>(src, dst, cur, csr, E);

    // 4. fused softmax + aggregation
    agg_kernel<<<M, 256, 0, stream>>>(proj, el, er, csr, ofs, deg, out);
}

// Round 3
// 391.727 us; speedup vs baseline: 1.4963x; 1.2620x over previous
//
#include <hip/hip_runtime.h>
#include <math.h>

#define D_IN 256
#define NH 8
#define DOUT 32
#define NOUT 256  // NH*DOUT
#define NEG_SLOPE 0.2f

// ---------------- GEMM: C[M,256] = A[M,256] @ B[256,256], fp32 ----------------
// 128x128 tile, BK=16, 256 threads, 8x8 per thread.
__global__ __launch_bounds__(256) void gemm_kernel(const float* __restrict__ A,
                                                   const float* __restrict__ B,
                                                   float* __restrict__ C, int M) {
    __shared__ float As[16][128];  // k-major
    __shared__ float Bs[16][128];
    int tid = threadIdx.x;
    int tx = tid & 15;   // col group
    int ty = tid >> 4;   // row group
    int row0 = blockIdx.y * 128;
    int col0 = blockIdx.x * 128;
    float acc[8][8] = {};

    for (int kb = 0; kb < D_IN; kb += 16) {
        int ar = tid >> 2;
        int ac = (tid & 3) * 4;
        float4 a0 = make_float4(0.f, 0.f, 0.f, 0.f), a1 = a0;
        int r0 = row0 + ar, r1 = row0 + ar + 64;
        if (r0 < M) a0 = *reinterpret_cast<const float4*>(&A[(size_t)r0 * D_IN + kb + ac]);
        if (r1 < M) a1 = *reinterpret_cast<const float4*>(&A[(size_t)r1 * D_IN + kb + ac]);
        As[ac + 0][ar] = a0.x; As[ac + 1][ar] = a0.y; As[ac + 2][ar] = a0.z; As[ac + 3][ar] = a0.w;
        As[ac + 0][ar + 64] = a1.x; As[ac + 1][ar + 64] = a1.y; As[ac + 2][ar + 64] = a1.z; As[ac + 3][ar + 64] = a1.w;
        int br = tid >> 4;
        int bc = (tid & 15) * 4;
        float4 b0 = *reinterpret_cast<const float4*>(&B[(size_t)(kb + br) * NOUT + col0 + bc]);
        float4 b1 = *reinterpret_cast<const float4*>(&B[(size_t)(kb + br) * NOUT + col0 + bc + 64]);
        *reinterpret_cast<float4*>(&Bs[br][bc]) = b0;
        *reinterpret_cast<float4*>(&Bs[br][bc + 64]) = b1;
        __syncthreads();
#pragma unroll
        for (int k = 0; k < 16; ++k) {
            float4 a0f = *reinterpret_cast<const float4*>(&As[k][ty * 4]);
            float4 a1f = *reinterpret_cast<const float4*>(&As[k][ty * 4 + 64]);
            float4 b0f = *reinterpret_cast<const float4*>(&Bs[k][tx * 4]);
            float4 b1f = *reinterpret_cast<const float4*>(&Bs[k][tx * 4 + 64]);
            float av[8] = {a0f.x, a0f.y, a0f.z, a0f.w, a1f.x, a1f.y, a1f.z, a1f.w};
            float bv[8] = {b0f.x, b0f.y, b0f.z, b0f.w, b1f.x, b1f.y, b1f.z, b1f.w};
#pragma unroll
            for (int i = 0; i < 8; ++i)
#pragma unroll
                for (int j = 0; j < 8; ++j) acc[i][j] += av[i] * bv[j];
        }
        __syncthreads();
    }
#pragma unroll
    for (int i = 0; i < 8; ++i) {
        int row = row0 + (i < 4 ? ty * 4 + i : 64 + ty * 4 + (i - 4));
        if (row < M) {
            float4 c0 = make_float4(acc[i][0], acc[i][1], acc[i][2], acc[i][3]);
            float4 c1 = make_float4(acc[i][4], acc[i][5], acc[i][6], acc[i][7]);
            *reinterpret_cast<float4*>(&C[(size_t)row * NOUT + col0 + tx * 4]) = c0;
            *reinterpret_cast<float4*>(&C[(size_t)row * NOUT + col0 + tx * 4 + 64]) = c1;
        }
    }
}

// ---------------- el/er: per-node attention logits ----------------
__global__ __launch_bounds__(256) void elr_kernel(const float* __restrict__ proj,
                                                  const float* __restrict__ al,
                                                  const float* __restrict__ ar,
                                                  float* __restrict__ el,
                                                  float* __restrict__ er, int N) {
    int n = blockIdx.x;
    int t = threadIdx.x;
    float p = proj[(size_t)n * NOUT + t];
    float l = p * al[t];
    float r = p * ar[t];
#pragma unroll
    for (int s = 16; s; s >>= 1) {
        l += __shfl_xor(l, s, 32);
        r += __shfl_xor(r, s, 32);
    }
    if ((t & 31) == 0) {
        int h = t >> 5;
        el[n * NH + h] = l;
        er[n * NH + h] = r;
    }
}

// ---------------- degree histogram ----------------
__global__ void hist_kernel(const int* __restrict__ dst, int* __restrict__ deg, int E) {
    int i = blockIdx.x * blockDim.x + threadIdx.x;
    if (i < E) atomicAdd(&deg[dst[i]], 1);
}

// ---------------- two-level scan ----------------
__global__ __launch_bounds__(256) void scan1_kernel(const int* __restrict__ deg,
                                                    int* __restrict__ off,
                                                    int* __restrict__ bsum, int N) {
    __shared__ int wls[4];
    int tid = threadIdx.x, lane = tid & 63, w = tid >> 6;
    int i = blockIdx.x * 256 + tid;
    int v = (i < N) ? deg[i] : 0;
    int s = v;
#pragma unroll
    for (int d = 1; d < 64; d <<= 1) {
        int t = __shfl_up(s, d, 64);
        if (lane >= d) s += t;
    }
    if (lane == 63) wls[w] = s;
    __syncthreads();
    int add = 0;
    for (int j = 0; j < w; ++j) add += wls[j];
    if (i < N) off[i] = s - v + add;
    if (tid == 255) bsum[blockIdx.x] = add + s;
}

__global__ __launch_bounds__(256) void scan2_kernel(int* __restrict__ bsum, int nb) {
    __shared__ int wls[4];
    __shared__ int carry;
    int tid = threadIdx.x, lane = tid & 63, w = tid >> 6;
    if (tid == 0) carry = 0;
    __syncthreads();
    for (int base = 0; base < nb; base += 256) {
        int i = base + tid;
        int v = (i < nb) ? bsum[i] : 0;
        int s = v;
#pragma unroll
        for (int d = 1; d < 64; d <<= 1) {
            int t = __shfl_up(s, d, 64);
            if (lane >= d) s += t;
        }
        if (lane == 63) wls[w] = s;
        __syncthreads();
        int add = carry;
        for (int j = 0; j < w; ++j) add += wls[j];
        int excl = s - v + add;
        int total = wls[0] + wls[1] + wls[2] + wls[3];
        __syncthreads();
        if (i < nb) bsum[i] = excl;
        if (tid == 0) carry += total;
        __syncthreads();
    }
}

__global__ __launch_bounds__(256) void scan3_kernel(int* __restrict__ off,
                                                    int* __restrict__ cur,
                                                    const int* __restrict__ bsum, int N) {
    int i = blockIdx.x * 256 + threadIdx.x;
    if (i < N) {
        int o = off[i] + bsum[blockIdx.x];
        off[i] = o;
        cur[i] = o;
    }
}

// ---------------- scatter SRC ids into CSR ----------------
__global__ void scatter_kernel(const int* __restrict__ src, const int* __restrict__ dst,
                               int* __restrict__ cur, int* __restrict__ csr, int E) {
    int i = blockIdx.x * blockDim.x + threadIdx.x;
    if (i < E) {
        int p = atomicAdd(&cur[dst[i]], 1);
        csr[p] = src[i];
    }
}

// ---------------- fused edge-softmax + aggregation, ONE WAVE per dst ----------------
// 4 waves / block, no __syncthreads. Per wave: lane k owns edge k (u + 8
// logits in regs); in-wave shfl reduces for max/sum; per-wave LDS slab for
// normalized weights (DS ops are in-order within a wave); gather broadcasts u
// via shfl and streams 1KB proj rows, unroll 8 for MLP.
__global__ __launch_bounds__(256) void agg_kernel(const float* __restrict__ proj,
                                                  const float* __restrict__ el,
                                                  const float* __restrict__ er,
                                                  const int* __restrict__ csrU,
                                                  const int* __restrict__ off,
                                                  const int* __restrict__ deg,
                                                  float* __restrict__ out, int N) {
    __shared__ float pS[4][64][NH + 1];  // 9-pad: conflict-free write & read
    __shared__ int uS[4][64];            // generic path only
    int w = threadIdx.x >> 6, lane = threadIdx.x & 63;
    int v = blockIdx.x * 4 + w;
    if (v >= N) return;
    int base = off[v];
    int n = deg[v];
    float4 acc = make_float4(0.f, 0.f, 0.f, 0.f);
    int h4 = lane >> 3;  // head of features lane*4 .. lane*4+3

    if (n > 0) {
        const float4* el4 = reinterpret_cast<const float4*>(el);
        const float4* er4 = reinterpret_cast<const float4*>(er);
        float4 e0 = er4[(size_t)v * 2], e1 = er4[(size_t)v * 2 + 1];
        float er_r[NH] = {e0.x, e0.y, e0.z, e0.w, e1.x, e1.y, e1.z, e1.w};

        if (n <= 64) {
            // ---- fast path: whole edge list in wave registers ----
            int u_reg = 0;
            float x[NH];
            bool act = lane < n;
            if (act) {
                u_reg = csrU[base + lane];
                float4 a0 = el4[(size_t)u_reg * 2], a1 = el4[(size_t)u_reg * 2 + 1];
                float xin[NH] = {a0.x, a0.y, a0.z, a0.w, a1.x, a1.y, a1.z, a1.w};
#pragma unroll
                for (int h = 0; h < NH; ++h) {
                    float t = xin[h] + er_r[h];
                    x[h] = (t > 0.f) ? t : NEG_SLOPE * t;
                }
            } else {
#pragma unroll
                for (int h = 0; h < NH; ++h) x[h] = -INFINITY;
            }
            float m[NH];
#pragma unroll
            for (int h = 0; h < NH; ++h) m[h] = x[h];
#pragma unroll
            for (int s = 32; s; s >>= 1)
#pragma unroll
                for (int h = 0; h < NH; ++h) m[h] = fmaxf(m[h], __shfl_xor(m[h], s, 64));
            float p[NH], sm[NH];
#pragma unroll
            for (int h = 0; h < NH; ++h) {
                p[h] = act ? __expf(x[h] - m[h]) : 0.f;
                sm[h] = p[h];
            }
#pragma unroll
            for (int s = 32; s; s >>= 1)
#pragma unroll
                for (int h = 0; h < NH; ++h) sm[h] += __shfl_xor(sm[h], s, 64);
#pragma unroll
            for (int h = 0; h < NH; ++h) pS[w][lane][h] = p[h] * (1.f / sm[h]);
            __builtin_amdgcn_wave_barrier();  // compile fence; DS in-order per wave

            int kk = 0;
            for (; kk + 8 <= n; kk += 8) {
#pragma unroll
                for (int j = 0; j < 8; ++j) {
                    int u = __shfl(u_reg, kk + j, 64);
                    float pp = pS[w][kk + j][h4];
                    float4 vv = *reinterpret_cast<const float4*>(&proj[(size_t)u * NOUT + lane * 4]);
                    acc.x += pp * vv.x; acc.y += pp * vv.y;
                    acc.z += pp * vv.z; acc.w += pp * vv.w;
                }
            }
            for (; kk < n; ++kk) {
                int u = __shfl(u_reg, kk, 64);
                float pp = pS[w][kk][h4];
                float4 vv = *reinterpret_cast<const float4*>(&proj[(size_t)u * NOUT + lane * 4]);
                acc.x += pp * vv.x; acc.y += pp * vv.y;
                acc.z += pp * vv.z; acc.w += pp * vv.w;
            }
        } else {
            // ---- generic path (n > 64): chunked 3-loop, rare ----
            float m[NH];
#pragma unroll
            for (int h = 0; h < NH; ++h) m[h] = -INFINITY;
            for (int c0 = 0; c0 < n; c0 += 64) {
                if (lane < n - c0) {
                    int u = csrU[base + c0 + lane];
                    float4 a0 = el4[(size_t)u * 2], a1 = el4[(size_t)u * 2 + 1];
                    float xin[NH] = {a0.x, a0.y, a0.z, a0.w, a1.x, a1.y, a1.z, a1.w};
#pragma unroll
                    for (int h = 0; h < NH; ++h) {
                        float t = xin[h] + er_r[h];
                        t = (t > 0.f) ? t : NEG_SLOPE * t;
                        m[h] = fmaxf(m[h], t);
                    }
                }
            }
#pragma unroll
            for (int s = 32; s; s >>= 1)
#pragma unroll
                for (int h = 0; h < NH; ++h) m[h] = fmaxf(m[h], __shfl_xor(m[h], s, 64));
            float sm[NH] = {};
            for (int c0 = 0; c0 < n; c0 += 64) {
                if (lane < n - c0) {
                    int u = csrU[base + c0 + lane];
                    float4 a0 = el4[(size_t)u * 2], a1 = el4[(size_t)u * 2 + 1];
                    float xin[NH] = {a0.x, a0.y, a0.z, a0.w, a1.x, a1.y, a1.z, a1.w};
#pragma unroll
                    for (int h = 0; h < NH; ++h) {
                        float t = xin[h] + er_r[h];
                        t = (t > 0.f) ? t : NEG_SLOPE * t;
                        sm[h] += __expf(t - m[h]);
                    }
                }
            }
#pragma unroll
            for (int s = 32; s; s >>= 1)
#pragma unroll
                for (int h = 0; h < NH; ++h) sm[h] += __shfl_xor(sm[h], s, 64);
            float inv[NH];
#pragma unroll
            for (int h = 0; h < NH; ++h) inv[h] = 1.f / sm[h];
            for (int c0 = 0; c0 < n; c0 += 64) {
                int cn = min(64, n - c0);
                if (lane < cn) {
                    int u = csrU[base + c0 + lane];
                    uS[w][lane] = u;
                    float4 a0 = el4[(size_t)u * 2], a1 = el4[(size_t)u * 2 + 1];
                    float xin[NH] = {a0.x, a0.y, a0.z, a0.w, a1.x, a1.y, a1.z, a1.w};
#pragma unroll
                    for (int h = 0; h < NH; ++h) {
                        float t = xin[h] + er_r[h];
                        t = (t > 0.f) ? t : NEG_SLOPE * t;
                        pS[w][lane][h] = __expf(t - m[h]) * inv[h];
                    }
                }
                __builtin_amdgcn_wave_barrier();
                for (int k = 0; k < cn; ++k) {
                    int u = uS[w][k];
                    float pp = pS[w][k][h4];
                    float4 vv = *reinterpret_cast<const float4*>(&proj[(size_t)u * NOUT + lane * 4]);
                    acc.x += pp * vv.x; acc.y += pp * vv.y;
                    acc.z += pp * vv.z; acc.w += pp * vv.w;
                }
                __builtin_amdgcn_wave_barrier();
            }
        }
    }
    *reinterpret_cast<float4*>(&out[(size_t)v * NOUT + lane * 4]) = acc;
}

extern "C" void kernel_launch(void* const* d_in, const int* in_sizes, int n_in,
                              void* d_out, int out_size, void* d_ws, size_t ws_size,
                              hipStream_t stream) {
    const float* feat   = (const float*)d_in[0];
    const float* W      = (const float*)d_in[1];
    const float* attn_l = (const float*)d_in[2];
    const float* attn_r = (const float*)d_in[3];
    const int*   src    = (const int*)d_in[4];
    const int*   dst    = (const int*)d_in[5];
    float* out = (float*)d_out;

    const int M = in_sizes[0] / D_IN;   // 50000
    const int E = in_sizes[4];          // 800000
    const int nb = (M + 255) / 256;

    char* ws = (char*)d_ws;
    size_t off_proj = 0;
    size_t off_el   = off_proj + (size_t)M * NOUT * 4;
    size_t off_er   = off_el   + (size_t)M * NH * 4;
    size_t off_deg  = off_er   + (size_t)M * NH * 4;
    size_t off_ofs  = off_deg  + (size_t)M * 4;
    size_t off_cur  = off_ofs  + (size_t)M * 4;
    size_t off_csr  = off_cur  + (size_t)M * 4;
    size_t off_bsum = off_csr  + (size_t)E * 4;

    float* proj = (float*)(ws + off_proj);
    float* el   = (float*)(ws + off_el);
    float* er   = (float*)(ws + off_er);
    int*   deg  = (int*)(ws + off_deg);
    int*   ofs  = (int*)(ws + off_ofs);
    int*   cur  = (int*)(ws + off_cur);
    int*   csr  = (int*)(ws + off_csr);
    int*   bsum = (int*)(ws + off_bsum);

    hipMemsetAsync(deg, 0, (size_t)M * 4, stream);

    // 1. projection GEMM
    dim3 ggrid(NOUT / 128, (M + 127) / 128);
    gemm_kernel<<<ggrid, 256, 0, stream>>>(feat, W, proj, M);

    // 2. el / er logits
    elr_kernel<<<M, 256, 0, stream>>>(proj, attn_l, attn_r, el, er, M);

    // 3. CSR build
    int eblocks = (E + 255) / 256;
    hist_kernel<<<eblocks, 256, 0, stream>>>(dst, deg, E);
    scan1_kernel<<<nb, 256, 0, stream>>>(deg, ofs, bsum, M);
    scan2_kernel<<<1, 256, 0, stream>>>(bsum, nb);
    scan3_kernel<<<nb, 256, 0, stream>>>(ofs, cur, bsum, M);
    scatter_kernel<<<eblocks, 256, 0, stream>>>(src, dst, cur, csr, E);

    // 4. fused softmax + aggregation (wave-per-dst)
    agg_kernel<<<(M + 3) / 4, 256, 0, stream>>>(proj, el, er, csr, ofs, deg, out, M);
}

// Round 4
// 299.112 us; speedup vs baseline: 1.9595x; 1.3096x over previous
//
#include <hip/hip_runtime.h>
#include <math.h>
#include <stdint.h>

#define D_IN 256
#define NH 8
#define DOUT 32
#define NOUT 256  // NH*DOUT
#define NEG_SLOPE 0.2f
#define LDP 40    // LDS row stride in shorts (80 B: 16B-aligned, <=2-way banks)

typedef short bf16x8 __attribute__((ext_vector_type(8)));
typedef float f32x4 __attribute__((ext_vector_type(4)));
typedef short short4v __attribute__((ext_vector_type(4)));

__device__ __forceinline__ short bf16_rne(float f) {
    uint32_t x = __float_as_uint(f);
    uint32_t r = (x + 0x7FFFu + ((x >> 16) & 1u)) >> 16;
    return (short)(uint16_t)r;
}
__device__ __forceinline__ float bf16_to_f(short h) {
    return __uint_as_float(((uint32_t)(uint16_t)h) << 16);
}

// ---------------- W prep: transpose + hi/lo bf16 split ----------------
// Bt[n][k] (k-major per output column) so B-fragments read 8 consecutive k.
__global__ __launch_bounds__(256) void bsplit_kernel(const float* __restrict__ W,
                                                     short* __restrict__ Bth,
                                                     short* __restrict__ Btl) {
    int n = blockIdx.x;
    int k = threadIdx.x;
    float w = W[(size_t)k * NOUT + n];
    short h = bf16_rne(w);
    short l = bf16_rne(w - bf16_to_f(h));
    Bth[(size_t)n * D_IN + k] = h;
    Btl[(size_t)n * D_IN + k] = l;
}

// ---------------- split-bf16 MFMA GEMM: proj = feat @ W ----------------
// BM=128, BN=256(full), BK=32. 4 waves; wave w owns rows [w*32,w*32+32).
// C = Ah*Bh + Al*Bh + Ah*Bl  (al*bl dropped, ~2^-18 rel err).
__global__ __launch_bounds__(256) void gemm_mfma_kernel(const float* __restrict__ A,
                                                        const short* __restrict__ Bth,
                                                        const short* __restrict__ Btl,
                                                        float* __restrict__ C, int M) {
    __shared__ short Ah[128][LDP], Al[128][LDP];   // 10240 B each
    __shared__ short Bh[256][LDP], Bl[256][LDP];   // 20480 B each
    int tid = threadIdx.x;
    int w = tid >> 6, lane = tid & 63;
    int l15 = lane & 15, l4 = lane >> 4;
    int row0 = blockIdx.x * 128;

    f32x4 acc[2][16];
#pragma unroll
    for (int mt = 0; mt < 2; ++mt)
#pragma unroll
        for (int nt = 0; nt < 16; ++nt)
#pragma unroll
            for (int i = 0; i < 4; ++i) acc[mt][nt][i] = 0.f;

    int rot = (tid >> 3) & 3;          // staging-write bank rotation
    int ar = tid >> 1;                 // A row (0..127), 2 threads/row
    int akb = (tid & 1) * 16;          // k-half within BK=32
    bool avalid = (row0 + ar) < M;
    const float* Abase = A + (size_t)(row0 + ar) * D_IN + akb;
    int bc = tid;                      // B column (0..255)
    const short* bhsrc0 = Bth + (size_t)bc * D_IN;
    const short* blsrc0 = Btl + (size_t)bc * D_IN;

    for (int kb = 0; kb < D_IN; kb += 32) {
        __syncthreads();
        // ---- stage A tile (fp32 -> hi/lo bf16), j-rotated writes ----
#pragma unroll
        for (int jj = 0; jj < 4; ++jj) {
            int j = (jj + rot) & 3;
            float4 v = make_float4(0.f, 0.f, 0.f, 0.f);
            if (avalid) v = *reinterpret_cast<const float4*>(Abase + kb + j * 4);
            short4v h, lo;
            h[0] = bf16_rne(v.x); h[1] = bf16_rne(v.y);
            h[2] = bf16_rne(v.z); h[3] = bf16_rne(v.w);
            lo[0] = bf16_rne(v.x - bf16_to_f(h[0]));
            lo[1] = bf16_rne(v.y - bf16_to_f(h[1]));
            lo[2] = bf16_rne(v.z - bf16_to_f(h[2]));
            lo[3] = bf16_rne(v.w - bf16_to_f(h[3]));
            *reinterpret_cast<short4v*>(&Ah[ar][akb + j * 4]) = h;
            *reinterpret_cast<short4v*>(&Al[ar][akb + j * 4]) = lo;
        }
        // ---- stage B slab (already bf16, k-major), j-rotated ----
#pragma unroll
        for (int jj = 0; jj < 4; ++jj) {
            int j = (jj + rot) & 3;
            int4 vh = *reinterpret_cast<const int4*>(bhsrc0 + kb + j * 8);
            int4 vl = *reinterpret_cast<const int4*>(blsrc0 + kb + j * 8);
            *reinterpret_cast<int4*>(&Bh[bc][j * 8]) = vh;
            *reinterpret_cast<int4*>(&Bl[bc][j * 8]) = vl;
        }
        __syncthreads();
        // ---- fragments + MFMA ----
        int arow = w * 32 + l15;
        bf16x8 ah0 = *reinterpret_cast<const bf16x8*>(&Ah[arow][l4 * 8]);
        bf16x8 ah1 = *reinterpret_cast<const bf16x8*>(&Ah[arow + 16][l4 * 8]);
        bf16x8 al0 = *reinterpret_cast<const bf16x8*>(&Al[arow][l4 * 8]);
        bf16x8 al1 = *reinterpret_cast<const bf16x8*>(&Al[arow + 16][l4 * 8]);
#pragma unroll
        for (int nt = 0; nt < 16; ++nt) {
            int col = nt * 16 + l15;
            bf16x8 bh = *reinterpret_cast<const bf16x8*>(&Bh[col][l4 * 8]);
            bf16x8 bl = *reinterpret_cast<const bf16x8*>(&Bl[col][l4 * 8]);
            acc[0][nt] = __builtin_amdgcn_mfma_f32_16x16x32_bf16(ah0, bh, acc[0][nt], 0, 0, 0);
            acc[1][nt] = __builtin_amdgcn_mfma_f32_16x16x32_bf16(ah1, bh, acc[1][nt], 0, 0, 0);
            acc[0][nt] = __builtin_amdgcn_mfma_f32_16x16x32_bf16(al0, bh, acc[0][nt], 0, 0, 0);
            acc[1][nt] = __builtin_amdgcn_mfma_f32_16x16x32_bf16(al1, bh, acc[1][nt], 0, 0, 0);
            acc[0][nt] = __builtin_amdgcn_mfma_f32_16x16x32_bf16(ah0, bl, acc[0][nt], 0, 0, 0);
            acc[1][nt] = __builtin_amdgcn_mfma_f32_16x16x32_bf16(ah1, bl, acc[1][nt], 0, 0, 0);
        }
    }
    // ---- epilogue: C/D layout col=lane&15, row=(lane>>4)*4+reg (m89) ----
#pragma unroll
    for (int mt = 0; mt < 2; ++mt) {
        int rowb = row0 + w * 32 + mt * 16 + l4 * 4;
#pragma unroll
        for (int r = 0; r < 4; ++r) {
            int row = rowb + r;
            if (row < M) {
#pragma unroll
                for (int nt = 0; nt < 16; ++nt)
                    C[(size_t)row * NOUT + nt * 16 + l15] = acc[mt][nt][r];
            }
        }
    }
}

// ---------------- el/er: per-node attention logits ----------------
__global__ __launch_bounds__(256) void elr_kernel(const float* __restrict__ proj,
                                                  const float* __restrict__ al,
                                                  const float* __restrict__ ar,
                                                  float* __restrict__ el,
                                                  float* __restrict__ er, int N) {
    int n = blockIdx.x;
    int t = threadIdx.x;
    float p = proj[(size_t)n * NOUT + t];
    float l = p * al[t];
    float r = p * ar[t];
#pragma unroll
    for (int s = 16; s; s >>= 1) {
        l += __shfl_xor(l, s, 32);
        r += __shfl_xor(r, s, 32);
    }
    if ((t & 31) == 0) {
        int h = t >> 5;
        el[n * NH + h] = l;
        er[n * NH + h] = r;
    }
}

// ---------------- degree histogram ----------------
__global__ void hist_kernel(const int* __restrict__ dst, int* __restrict__ deg, int E) {
    int i = blockIdx.x * blockDim.x + threadIdx.x;
    if (i < E) atomicAdd(&deg[dst[i]], 1);
}

// ---------------- two-level scan ----------------
__global__ __launch_bounds__(256) void scan1_kernel(const int* __restrict__ deg,
                                                    int* __restrict__ off,
                                                    int* __restrict__ bsum, int N) {
    __shared__ int wls[4];
    int tid = threadIdx.x, lane = tid & 63, w = tid >> 6;
    int i = blockIdx.x * 256 + tid;
    int v = (i < N) ? deg[i] : 0;
    int s = v;
#pragma unroll
    for (int d = 1; d < 64; d <<= 1) {
        int t = __shfl_up(s, d, 64);
        if (lane >= d) s += t;
    }
    if (lane == 63) wls[w] = s;
    __syncthreads();
    int add = 0;
    for (int j = 0; j < w; ++j) add += wls[j];
    if (i < N) off[i] = s - v + add;
    if (tid == 255) bsum[blockIdx.x] = add + s;
}

__global__ __launch_bounds__(256) void scan2_kernel(int* __restrict__ bsum, int nb) {
    __shared__ int wls[4];
    __shared__ int carry;
    int tid = threadIdx.x, lane = tid & 63, w = tid >> 6;
    if (tid == 0) carry = 0;
    __syncthreads();
    for (int base = 0; base < nb; base += 256) {
        int i = base + tid;
        int v = (i < nb) ? bsum[i] : 0;
        int s = v;
#pragma unroll
        for (int d = 1; d < 64; d <<= 1) {
            int t = __shfl_up(s, d, 64);
            if (lane >= d) s += t;
        }
        if (lane == 63) wls[w] = s;
        __syncthreads();
        int add = carry;
        for (int j = 0; j < w; ++j) add += wls[j];
        int excl = s - v + add;
        int total = wls[0] + wls[1] + wls[2] + wls[3];
        __syncthreads();
        if (i < nb) bsum[i] = excl;
        if (tid == 0) carry += total;
        __syncthreads();
    }
}

__global__ __launch_bounds__(256) void scan3_kernel(int* __restrict__ off,
                                                    int* __restrict__ cur,
                                                    const int* __restrict__ bsum, int N) {
    int i = blockIdx.x * 256 + threadIdx.x;
    if (i < N) {
        int o = off[i] + bsum[blockIdx.x];
        off[i] = o;
        cur[i] = o;
    }
}

// ---------------- scatter SRC ids into CSR ----------------
__global__ void scatter_kernel(const int* __restrict__ src, const int* __restrict__ dst,
                               int* __restrict__ cur, int* __restrict__ csr, int E) {
    int i = blockIdx.x * blockDim.x + threadIdx.x;
    if (i < E) {
        int p = atomicAdd(&cur[dst[i]], 1);
        csr[p] = src[i];
    }
}

// ---------------- fused edge-softmax + aggregation, ONE WAVE per dst ----------------
__global__ __launch_bounds__(256) void agg_kernel(const float* __restrict__ proj,
                                                  const float* __restrict__ el,
                                                  const float* __restrict__ er,
                                                  const int* __restrict__ csrU,
                                                  const int* __restrict__ off,
                                                  const int* __restrict__ deg,
                                                  float* __restrict__ out, int N) {
    __shared__ float pS[4][64][NH + 1];
    __shared__ int uS[4][64];
    int w = threadIdx.x >> 6, lane = threadIdx.x & 63;
    int v = blockIdx.x * 4 + w;
    if (v >= N) return;
    int base = off[v];
    int n = deg[v];
    float4 acc = make_float4(0.f, 0.f, 0.f, 0.f);
    int h4 = lane >> 3;

    if (n > 0) {
        const float4* el4 = reinterpret_cast<const float4*>(el);
        const float4* er4 = reinterpret_cast<const float4*>(er);
        float4 e0 = er4[(size_t)v * 2], e1 = er4[(size_t)v * 2 + 1];
        float er_r[NH] = {e0.x, e0.y, e0.z, e0.w, e1.x, e1.y, e1.z, e1.w};

        if (n <= 64) {
            int u_reg = 0;
            float x[NH];
            bool act = lane < n;
            if (act) {
                u_reg = csrU[base + lane];
                float4 a0 = el4[(size_t)u_reg * 2], a1 = el4[(size_t)u_reg * 2 + 1];
                float xin[NH] = {a0.x, a0.y, a0.z, a0.w, a1.x, a1.y, a1.z, a1.w};
#pragma unroll
                for (int h = 0; h < NH; ++h) {
                    float t = xin[h] + er_r[h];
                    x[h] = (t > 0.f) ? t : NEG_SLOPE * t;
                }
            } else {
#pragma unroll
                for (int h = 0; h < NH; ++h) x[h] = -INFINITY;
            }
            float m[NH];
#pragma unroll
            for (int h = 0; h < NH; ++h) m[h] = x[h];
#pragma unroll
            for (int s = 32; s; s >>= 1)
#pragma unroll
                for (int h = 0; h < NH; ++h) m[h] = fmaxf(m[h], __shfl_xor(m[h], s, 64));
            float p[NH], sm[NH];
#pragma unroll
            for (int h = 0; h < NH; ++h) {
                p[h] = act ? __expf(x[h] - m[h]) : 0.f;
                sm[h] = p[h];
            }
#pragma unroll
            for (int s = 32; s; s >>= 1)
#pragma unroll
                for (int h = 0; h < NH; ++h) sm[h] += __shfl_xor(sm[h], s, 64);
#pragma unroll
            for (int h = 0; h < NH; ++h) pS[w][lane][h] = p[h] * (1.f / sm[h]);
            __builtin_amdgcn_wave_barrier();

            int kk = 0;
            for (; kk + 8 <= n; kk += 8) {
#pragma unroll
                for (int j = 0; j < 8; ++j) {
                    int u = __shfl(u_reg, kk + j, 64);
                    float pp = pS[w][kk + j][h4];
                    float4 vv = *reinterpret_cast<const float4*>(&proj[(size_t)u * NOUT + lane * 4]);
                    acc.x += pp * vv.x; acc.y += pp * vv.y;
                    acc.z += pp * vv.z; acc.w += pp * vv.w;
                }
            }
            for (; kk < n; ++kk) {
                int u = __shfl(u_reg, kk, 64);
                float pp = pS[w][kk][h4];
                float4 vv = *reinterpret_cast<const float4*>(&proj[(size_t)u * NOUT + lane * 4]);
                acc.x += pp * vv.x; acc.y += pp * vv.y;
                acc.z += pp * vv.z; acc.w += pp * vv.w;
            }
        } else {
            float m[NH];
#pragma unroll
            for (int h = 0; h < NH; ++h) m[h] = -INFINITY;
            for (int c0 = 0; c0 < n; c0 += 64) {
                if (lane < n - c0) {
                    int u = csrU[base + c0 + lane];
                    float4 a0 = el4[(size_t)u * 2], a1 = el4[(size_t)u * 2 + 1];
                    float xin[NH] = {a0.x, a0.y, a0.z, a0.w, a1.x, a1.y, a1.z, a1.w};
#pragma unroll
                    for (int h = 0; h < NH; ++h) {
                        float t = xin[h] + er_r[h];
                        t = (t > 0.f) ? t : NEG_SLOPE * t;
                        m[h] = fmaxf(m[h], t);
                    }
                }
            }
#pragma unroll
            for (int s = 32; s; s >>= 1)
#pragma unroll
                for (int h = 0; h < NH; ++h) m[h] = fmaxf(m[h], __shfl_xor(m[h], s, 64));
            float sm[NH] = {};
            for (int c0 = 0; c0 < n; c0 += 64) {
                if (lane < n - c0) {
                    int u = csrU[base + c0 + lane];
                    float4 a0 = el4[(size_t)u * 2], a1 = el4[(size_t)u * 2 + 1];
                    float xin[NH] = {a0.x, a0.y, a0.z, a0.w, a1.x, a1.y, a1.z, a1.w};
#pragma unroll
                    for (int h = 0; h < NH; ++h) {
                        float t = xin[h] + er_r[h];
                        t = (t > 0.f) ? t : NEG_SLOPE * t;
                        sm[h] += __expf(t - m[h]);
                    }
                }
            }
#pragma unroll
            for (int s = 32; s; s >>= 1)
#pragma unroll
                for (int h = 0; h < NH; ++h) sm[h] += __shfl_xor(sm[h], s, 64);
            float inv[NH];
#pragma unroll
            for (int h = 0; h < NH; ++h) inv[h] = 1.f / sm[h];
            for (int c0 = 0; c0 < n; c0 += 64) {
                int cn = min(64, n - c0);
                if (lane < cn) {
                    int u = csrU[base + c0 + lane];
                    uS[w][lane] = u;
                    float4 a0 = el4[(size_t)u * 2], a1 = el4[(size_t)u * 2 + 1];
                    float xin[NH] = {a0.x, a0.y, a0.z, a0.w, a1.x, a1.y, a1.z, a1.w};
#pragma unroll
                    for (int h = 0; h < NH; ++h) {
                        float t = xin[h] + er_r[h];
                        t = (t > 0.f) ? t : NEG_SLOPE * t;
                        pS[w][lane][h] = __expf(t - m[h]) * inv[h];
                    }
                }
                __builtin_amdgcn_wave_barrier();
                for (int k = 0; k < cn; ++k) {
                    int u = uS[w][k];
                    float pp = pS[w][k][h4];
                    float4 vv = *reinterpret_cast<const float4*>(&proj[(size_t)u * NOUT + lane * 4]);
                    acc.x += pp * vv.x; acc.y += pp * vv.y;
                    acc.z += pp * vv.z; acc.w += pp * vv.w;
                }
                __builtin_amdgcn_wave_barrier();
            }
        }
    }
    *reinterpret_cast<float4*>(&out[(size_t)v * NOUT + lane * 4]) = acc;
}

extern "C" void kernel_launch(void* const* d_in, const int* in_sizes, int n_in,
                              void* d_out, int out_size, void* d_ws, size_t ws_size,
                              hipStream_t stream) {
    const float* feat   = (const float*)d_in[0];
    const float* W      = (const float*)d_in[1];
    const float* attn_l = (const float*)d_in[2];
    const float* attn_r = (const float*)d_in[3];
    const int*   src    = (const int*)d_in[4];
    const int*   dst    = (const int*)d_in[5];
    float* out = (float*)d_out;

    const int M = in_sizes[0] / D_IN;   // 50000
    const int E = in_sizes[4];          // 800000
    const int nb = (M + 255) / 256;

    char* ws = (char*)d_ws;
    size_t off_proj = 0;
    size_t off_el   = off_proj + (size_t)M * NOUT * 4;
    size_t off_er   = off_el   + (size_t)M * NH * 4;
    size_t off_deg  = off_er   + (size_t)M * NH * 4;
    size_t off_ofs  = off_deg  + (size_t)M * 4;
    size_t off_cur  = off_ofs  + (size_t)M * 4;
    size_t off_csr  = off_cur  + (size_t)M * 4;
    size_t off_bsum = off_csr  + (size_t)E * 4;
    size_t off_bth  = off_bsum + (size_t)nb * 4;
    off_bth = (off_bth + 255) & ~(size_t)255;
    size_t off_btl  = off_bth + (size_t)D_IN * NOUT * 2;

    float* proj = (float*)(ws + off_proj);
    float* el   = (float*)(ws + off_el);
    float* er   = (float*)(ws + off_er);
    int*   deg  = (int*)(ws + off_deg);
    int*   ofs  = (int*)(ws + off_ofs);
    int*   cur  = (int*)(ws + off_cur);
    int*   csr  = (int*)(ws + off_csr);
    int*   bsum = (int*)(ws + off_bsum);
    short* bth  = (short*)(ws + off_bth);
    short* btl  = (short*)(ws + off_btl);

    hipMemsetAsync(deg, 0, (size_t)M * 4, stream);

    // 1. W split + projection GEMM (split-bf16 MFMA)
    bsplit_kernel<<<NOUT, D_IN, 0, stream>>>(W, bth, btl);
    gemm_mfma_kernel<<<(M + 127) / 128, 256, 0, stream>>>(feat, bth, btl, proj, M);

    // 2. el / er logits
    elr_kernel<<<M, 256, 0, stream>>>(proj, attn_l, attn_r, el, er, M);

    // 3. CSR build
    int eblocks = (E + 255) / 256;
    hist_kernel<<<eblocks, 256, 0, stream>>>(dst, deg, E);
    scan1_kernel<<<nb, 256, 0, stream>>>(deg, ofs, bsum, M);
    scan2_kernel<<<1, 256, 0, stream>>>(bsum, nb);
    scan3_kernel<<<nb, 256, 0, stream>>>(ofs, cur, bsum, M);
    scatter_kernel<<<eblocks, 256, 0, stream>>>(src, dst, cur, csr, E);

    // 4. fused softmax + aggregation (wave-per-dst)
    agg_kernel<<<(M + 3) / 4, 256, 0, stream>>>(proj, el, er, csr, ofs, deg, out, M);
}

// Round 5
// 277.439 us; speedup vs baseline: 2.1126x; 1.0781x over previous
//
#include <hip/hip_runtime.h>
#include <math.h>
#include <stdint.h>

#define D_IN 256
#define NH 8
#define DOUT 32
#define NOUT 256  // NH*DOUT
#define NEG_SLOPE 0.2f
#define LDP 40    // LDS row stride in shorts (80 B: 16B-aligned, <=2-way banks)

typedef short bf16x8 __attribute__((ext_vector_type(8)));
typedef float f32x4 __attribute__((ext_vector_type(4)));
typedef short short8v __attribute__((ext_vector_type(8)));
typedef unsigned short u16x4 __attribute__((ext_vector_type(4)));

__device__ __forceinline__ short bf16_rne(float f) {
    uint32_t x = __float_as_uint(f);
    uint32_t r = (x + 0x7FFFu + ((x >> 16) & 1u)) >> 16;
    return (short)(uint16_t)r;
}
__device__ __forceinline__ float bf16_to_f(short h) {
    return __uint_as_float(((uint32_t)(uint16_t)h) << 16);
}
__device__ __forceinline__ float bfu_to_f(unsigned short h) {
    return __uint_as_float(((uint32_t)h) << 16);
}

// ---------------- A prep: hi/lo bf16 split (row-major, same layout) ----------------
__global__ __launch_bounds__(256) void asplit_kernel(const float* __restrict__ A,
                                                     short* __restrict__ Ahh,
                                                     short* __restrict__ All, int total8) {
    int i = blockIdx.x * 256 + threadIdx.x;
    if (i >= total8) return;
    const float4* a4 = reinterpret_cast<const float4*>(A);
    float4 v0 = a4[(size_t)i * 2];
    float4 v1 = a4[(size_t)i * 2 + 1];
    float vs[8] = {v0.x, v0.y, v0.z, v0.w, v1.x, v1.y, v1.z, v1.w};
    short8v h, l;
#pragma unroll
    for (int j = 0; j < 8; ++j) {
        h[j] = bf16_rne(vs[j]);
        l[j] = bf16_rne(vs[j] - bf16_to_f(h[j]));
    }
    reinterpret_cast<short8v*>(Ahh)[i] = h;
    reinterpret_cast<short8v*>(All)[i] = l;
}

// ---------------- W prep: transpose + hi/lo bf16 split ----------------
__global__ __launch_bounds__(256) void bsplit_kernel(const float* __restrict__ W,
                                                     short* __restrict__ Bth,
                                                     short* __restrict__ Btl) {
    int n = blockIdx.x;
    int k = threadIdx.x;
    float w = W[(size_t)k * NOUT + n];
    short h = bf16_rne(w);
    short l = bf16_rne(w - bf16_to_f(h));
    Bth[(size_t)n * D_IN + k] = h;
    Btl[(size_t)n * D_IN + k] = l;
}

// ---------------- split-bf16 MFMA GEMM + fused el/er + bf16 proj out ----------------
// BM=128, BN=256(full), BK=32. C = Ah*Bh + Al*Bh + Ah*Bl.
__global__ __launch_bounds__(256) void gemm_mfma_kernel(const short* __restrict__ Ahh,
                                                        const short* __restrict__ All,
                                                        const short* __restrict__ Bth,
                                                        const short* __restrict__ Btl,
                                                        const float* __restrict__ attn_l,
                                                        const float* __restrict__ attn_r,
                                                        short* __restrict__ projh,
                                                        float* __restrict__ el,
                                                        float* __restrict__ er, int M) {
    __shared__ short Ah[128][LDP], Al[128][LDP];
    __shared__ short Bh[256][LDP], Bl[256][LDP];
    int tid = threadIdx.x;
    int w = tid >> 6, lane = tid & 63;
    int l15 = lane & 15, l4 = lane >> 4;
    int row0 = blockIdx.x * 128;

    f32x4 acc[2][16];
#pragma unroll
    for (int mt = 0; mt < 2; ++mt)
#pragma unroll
        for (int nt = 0; nt < 16; ++nt)
#pragma unroll
            for (int i = 0; i < 4; ++i) acc[mt][nt][i] = 0.f;

    int rot = (tid >> 3) & 3;
    int ar = tid >> 1;                 // A row (0..127)
    int ks = (tid & 1) * 16;           // k-half within BK=32
    bool avalid = (row0 + ar) < M;
    const short* ahsrc = Ahh + (size_t)(row0 + ar) * D_IN + ks;
    const short* alsrc = All + (size_t)(row0 + ar) * D_IN + ks;
    int bc = tid;                      // B column (0..255)
    const short* bhsrc0 = Bth + (size_t)bc * D_IN;
    const short* blsrc0 = Btl + (size_t)bc * D_IN;
    const int4 zero4 = make_int4(0, 0, 0, 0);

    for (int kb = 0; kb < D_IN; kb += 32) {
        __syncthreads();
        // ---- stage A tile (pure copies, already bf16) ----
        {
            int4 h0 = avalid ? *reinterpret_cast<const int4*>(ahsrc + kb) : zero4;
            int4 h1 = avalid ? *reinterpret_cast<const int4*>(ahsrc + kb + 8) : zero4;
            int4 l0 = avalid ? *reinterpret_cast<const int4*>(alsrc + kb) : zero4;
            int4 l1 = avalid ? *reinterpret_cast<const int4*>(alsrc + kb + 8) : zero4;
            *reinterpret_cast<int4*>(&Ah[ar][ks]) = h0;
            *reinterpret_cast<int4*>(&Ah[ar][ks + 8]) = h1;
            *reinterpret_cast<int4*>(&Al[ar][ks]) = l0;
            *reinterpret_cast<int4*>(&Al[ar][ks + 8]) = l1;
        }
        // ---- stage B slab, j-rotated ----
#pragma unroll
        for (int jj = 0; jj < 4; ++jj) {
            int j = (jj + rot) & 3;
            int4 vh = *reinterpret_cast<const int4*>(bhsrc0 + kb + j * 8);
            int4 vl = *reinterpret_cast<const int4*>(blsrc0 + kb + j * 8);
            *reinterpret_cast<int4*>(&Bh[bc][j * 8]) = vh;
            *reinterpret_cast<int4*>(&Bl[bc][j * 8]) = vl;
        }
        __syncthreads();
        // ---- fragments + MFMA ----
        int arow = w * 32 + l15;
        bf16x8 ah0 = *reinterpret_cast<const bf16x8*>(&Ah[arow][l4 * 8]);
        bf16x8 ah1 = *reinterpret_cast<const bf16x8*>(&Ah[arow + 16][l4 * 8]);
        bf16x8 al0 = *reinterpret_cast<const bf16x8*>(&Al[arow][l4 * 8]);
        bf16x8 al1 = *reinterpret_cast<const bf16x8*>(&Al[arow + 16][l4 * 8]);
#pragma unroll
        for (int nt = 0; nt < 16; ++nt) {
            int col = nt * 16 + l15;
            bf16x8 bh = *reinterpret_cast<const bf16x8*>(&Bh[col][l4 * 8]);
            bf16x8 bl = *reinterpret_cast<const bf16x8*>(&Bl[col][l4 * 8]);
            acc[0][nt] = __builtin_amdgcn_mfma_f32_16x16x32_bf16(ah0, bh, acc[0][nt], 0, 0, 0);
            acc[1][nt] = __builtin_amdgcn_mfma_f32_16x16x32_bf16(ah1, bh, acc[1][nt], 0, 0, 0);
            acc[0][nt] = __builtin_amdgcn_mfma_f32_16x16x32_bf16(al0, bh, acc[0][nt], 0, 0, 0);
            acc[1][nt] = __builtin_amdgcn_mfma_f32_16x16x32_bf16(al1, bh, acc[1][nt], 0, 0, 0);
            acc[0][nt] = __builtin_amdgcn_mfma_f32_16x16x32_bf16(ah0, bl, acc[0][nt], 0, 0, 0);
            acc[1][nt] = __builtin_amdgcn_mfma_f32_16x16x32_bf16(ah1, bl, acc[1][nt], 0, 0, 0);
        }
    }

    // ---- epilogue: bf16 proj + fused el/er ----
    float alf[16], arf[16];
#pragma unroll
    for (int nt = 0; nt < 16; ++nt) {
        alf[nt] = attn_l[nt * 16 + l15];
        arf[nt] = attn_r[nt * 16 + l15];
    }
#pragma unroll
    for (int mt = 0; mt < 2; ++mt) {
        int rowb = row0 + w * 32 + mt * 16 + l4 * 4;
#pragma unroll
        for (int r = 0; r < 4; ++r) {
            int row = rowb + r;
            bool rv_ok = row < M;
            if (rv_ok) {
#pragma unroll
                for (int nt = 0; nt < 16; ++nt)
                    projh[(size_t)row * NOUT + nt * 16 + l15] = bf16_rne(acc[mt][nt][r]);
            }
            float ev[NH], rv[NH];
#pragma unroll
            for (int h = 0; h < NH; ++h) {
                ev[h] = acc[mt][2 * h][r] * alf[2 * h] + acc[mt][2 * h + 1][r] * alf[2 * h + 1];
                rv[h] = acc[mt][2 * h][r] * arf[2 * h] + acc[mt][2 * h + 1][r] * arf[2 * h + 1];
            }
#pragma unroll
            for (int s = 1; s < 16; s <<= 1) {
#pragma unroll
                for (int h = 0; h < NH; ++h) {
                    ev[h] += __shfl_xor(ev[h], s, 64);
                    rv[h] += __shfl_xor(rv[h], s, 64);
                }
            }
            if (l15 == 0 && rv_ok) {
#pragma unroll
                for (int h = 0; h < NH; ++h) {
                    el[(size_t)row * NH + h] = ev[h];
                    er[(size_t)row * NH + h] = rv[h];
                }
            }
        }
    }
}

// ---------------- degree histogram ----------------
__global__ void hist_kernel(const int* __restrict__ dst, int* __restrict__ deg, int E) {
    int i = blockIdx.x * blockDim.x + threadIdx.x;
    if (i < E) atomicAdd(&deg[dst[i]], 1);
}

// ---------------- two-level scan ----------------
__global__ __launch_bounds__(256) void scan1_kernel(const int* __restrict__ deg,
                                                    int* __restrict__ off,
                                                    int* __restrict__ bsum, int N) {
    __shared__ int wls[4];
    int tid = threadIdx.x, lane = tid & 63, w = tid >> 6;
    int i = blockIdx.x * 256 + tid;
    int v = (i < N) ? deg[i] : 0;
    int s = v;
#pragma unroll
    for (int d = 1; d < 64; d <<= 1) {
        int t = __shfl_up(s, d, 64);
        if (lane >= d) s += t;
    }
    if (lane == 63) wls[w] = s;
    __syncthreads();
    int add = 0;
    for (int j = 0; j < w; ++j) add += wls[j];
    if (i < N) off[i] = s - v + add;
    if (tid == 255) bsum[blockIdx.x] = add + s;
}

__global__ __launch_bounds__(256) void scan2_kernel(int* __restrict__ bsum, int nb) {
    __shared__ int wls[4];
    __shared__ int carry;
    int tid = threadIdx.x, lane = tid & 63, w = tid >> 6;
    if (tid == 0) carry = 0;
    __syncthreads();
    for (int base = 0; base < nb; base += 256) {
        int i = base + tid;
        int v = (i < nb) ? bsum[i] : 0;
        int s = v;
#pragma unroll
        for (int d = 1; d < 64; d <<= 1) {
            int t = __shfl_up(s, d, 64);
            if (lane >= d) s += t;
        }
        if (lane == 63) wls[w] = s;
        __syncthreads();
        int add = carry;
        for (int j = 0; j < w; ++j) add += wls[j];
        int excl = s - v + add;
        int total = wls[0] + wls[1] + wls[2] + wls[3];
        __syncthreads();
        if (i < nb) bsum[i] = excl;
        if (tid == 0) carry += total;
        __syncthreads();
    }
}

__global__ __launch_bounds__(256) void scan3_kernel(int* __restrict__ off,
                                                    int* __restrict__ cur,
                                                    const int* __restrict__ bsum, int N) {
    int i = blockIdx.x * 256 + threadIdx.x;
    if (i < N) {
        int o = off[i] + bsum[blockIdx.x];
        off[i] = o;
        cur[i] = o;
    }
}

// ---------------- scatter SRC ids into CSR ----------------
__global__ void scatter_kernel(const int* __restrict__ src, const int* __restrict__ dst,
                               int* __restrict__ cur, int* __restrict__ csr, int E) {
    int i = blockIdx.x * blockDim.x + threadIdx.x;
    if (i < E) {
        int p = atomicAdd(&cur[dst[i]], 1);
        csr[p] = src[i];
    }
}

// ---------------- fused edge-softmax + aggregation, ONE WAVE per dst ----------------
// Gather reads bf16 proj rows (512B each): half the traffic of fp32.
__global__ __launch_bounds__(256) void agg_kernel(const unsigned short* __restrict__ projh,
                                                  const float* __restrict__ el,
                                                  const float* __restrict__ er,
                                                  const int* __restrict__ csrU,
                                                  const int* __restrict__ off,
                                                  const int* __restrict__ deg,
                                                  float* __restrict__ out, int N) {
    __shared__ float pS[4][64][NH + 1];
    __shared__ int uS[4][64];
    int w = threadIdx.x >> 6, lane = threadIdx.x & 63;
    int v = blockIdx.x * 4 + w;
    if (v >= N) return;
    int base = off[v];
    int n = deg[v];
    float4 acc = make_float4(0.f, 0.f, 0.f, 0.f);
    int h4 = lane >> 3;

    if (n > 0) {
        const float4* el4 = reinterpret_cast<const float4*>(el);
        const float4* er4 = reinterpret_cast<const float4*>(er);
        float4 e0 = er4[(size_t)v * 2], e1 = er4[(size_t)v * 2 + 1];
        float er_r[NH] = {e0.x, e0.y, e0.z, e0.w, e1.x, e1.y, e1.z, e1.w};

        if (n <= 64) {
            int u_reg = 0;
            float x[NH];
            bool act = lane < n;
            if (act) {
                u_reg = csrU[base + lane];
                float4 a0 = el4[(size_t)u_reg * 2], a1 = el4[(size_t)u_reg * 2 + 1];
                float xin[NH] = {a0.x, a0.y, a0.z, a0.w, a1.x, a1.y, a1.z, a1.w};
#pragma unroll
                for (int h = 0; h < NH; ++h) {
                    float t = xin[h] + er_r[h];
                    x[h] = (t > 0.f) ? t : NEG_SLOPE * t;
                }
            } else {
#pragma unroll
                for (int h = 0; h < NH; ++h) x[h] = -INFINITY;
            }
            float m[NH];
#pragma unroll
            for (int h = 0; h < NH; ++h) m[h] = x[h];
#pragma unroll
            for (int s = 32; s; s >>= 1)
#pragma unroll
                for (int h = 0; h < NH; ++h) m[h] = fmaxf(m[h], __shfl_xor(m[h], s, 64));
            float p[NH], sm[NH];
#pragma unroll
            for (int h = 0; h < NH; ++h) {
                p[h] = act ? __expf(x[h] - m[h]) : 0.f;
                sm[h] = p[h];
            }
#pragma unroll
            for (int s = 32; s; s >>= 1)
#pragma unroll
                for (int h = 0; h < NH; ++h) sm[h] += __shfl_xor(sm[h], s, 64);
#pragma unroll
            for (int h = 0; h < NH; ++h) pS[w][lane][h] = p[h] * (1.f / sm[h]);
            __builtin_amdgcn_wave_barrier();

            int kk = 0;
            for (; kk + 8 <= n; kk += 8) {
#pragma unroll
                for (int j = 0; j < 8; ++j) {
                    int u = __shfl(u_reg, kk + j, 64);
                    float pp = pS[w][kk + j][h4];
                    u16x4 vv = *reinterpret_cast<const u16x4*>(&projh[(size_t)u * NOUT + lane * 4]);
                    acc.x += pp * bfu_to_f(vv[0]);
                    acc.y += pp * bfu_to_f(vv[1]);
                    acc.z += pp * bfu_to_f(vv[2]);
                    acc.w += pp * bfu_to_f(vv[3]);
                }
            }
            for (; kk < n; ++kk) {
                int u = __shfl(u_reg, kk, 64);
                float pp = pS[w][kk][h4];
                u16x4 vv = *reinterpret_cast<const u16x4*>(&projh[(size_t)u * NOUT + lane * 4]);
                acc.x += pp * bfu_to_f(vv[0]);
                acc.y += pp * bfu_to_f(vv[1]);
                acc.z += pp * bfu_to_f(vv[2]);
                acc.w += pp * bfu_to_f(vv[3]);
            }
        } else {
            float m[NH];
#pragma unroll
            for (int h = 0; h < NH; ++h) m[h] = -INFINITY;
            for (int c0 = 0; c0 < n; c0 += 64) {
                if (lane < n - c0) {
                    int u = csrU[base + c0 + lane];
                    float4 a0 = el4[(size_t)u * 2], a1 = el4[(size_t)u * 2 + 1];
                    float xin[NH] = {a0.x, a0.y, a0.z, a0.w, a1.x, a1.y, a1.z, a1.w};
#pragma unroll
                    for (int h = 0; h < NH; ++h) {
                        float t = xin[h] + er_r[h];
                        t = (t > 0.f) ? t : NEG_SLOPE * t;
                        m[h] = fmaxf(m[h], t);
                    }
                }
            }
#pragma unroll
            for (int s = 32; s; s >>= 1)
#pragma unroll
                for (int h = 0; h < NH; ++h) m[h] = fmaxf(m[h], __shfl_xor(m[h], s, 64));
            float sm[NH] = {};
            for (int c0 = 0; c0 < n; c0 += 64) {
                if (lane < n - c0) {
                    int u = csrU[base + c0 + lane];
                    float4 a0 = el4[(size_t)u * 2], a1 = el4[(size_t)u * 2 + 1];
                    float xin[NH] = {a0.x, a0.y, a0.z, a0.w, a1.x, a1.y, a1.z, a1.w};
#pragma unroll
                    for (int h = 0; h < NH; ++h) {
                        float t = xin[h] + er_r[h];
                        t = (t > 0.f) ? t : NEG_SLOPE * t;
                        sm[h] += __expf(t - m[h]);
                    }
                }
            }
#pragma unroll
            for (int s = 32; s; s >>= 1)
#pragma unroll
                for (int h = 0; h < NH; ++h) sm[h] += __shfl_xor(sm[h], s, 64);
            float inv[NH];
#pragma unroll
            for (int h = 0; h < NH; ++h) inv[h] = 1.f / sm[h];
            for (int c0 = 0; c0 < n; c0 += 64) {
                int cn = min(64, n - c0);
                if (lane < cn) {
                    int u = csrU[base + c0 + lane];
                    uS[w][lane] = u;
                    float4 a0 = el4[(size_t)u * 2], a1 = el4[(size_t)u * 2 + 1];
                    float xin[NH] = {a0.x, a0.y, a0.z, a0.w, a1.x, a1.y, a1.z, a1.w};
#pragma unroll
                    for (int h = 0; h < NH; ++h) {
                        float t = xin[h] + er_r[h];
                        t = (t > 0.f) ? t : NEG_SLOPE * t;
                        pS[w][lane][h] = __expf(t - m[h]) * inv[h];
                    }
                }
                __builtin_amdgcn_wave_barrier();
                for (int k = 0; k < cn; ++k) {
                    int u = uS[w][k];
                    float pp = pS[w][k][h4];
                    u16x4 vv = *reinterpret_cast<const u16x4*>(&projh[(size_t)u * NOUT + lane * 4]);
                    acc.x += pp * bfu_to_f(vv[0]);
                    acc.y += pp * bfu_to_f(vv[1]);
                    acc.z += pp * bfu_to_f(vv[2]);
                    acc.w += pp * bfu_to_f(vv[3]);
                }
                __builtin_amdgcn_wave_barrier();
            }
        }
    }
    *reinterpret_cast<float4*>(&out[(size_t)v * NOUT + lane * 4]) = acc;
}

extern "C" void kernel_launch(void* const* d_in, const int* in_sizes, int n_in,
                              void* d_out, int out_size, void* d_ws, size_t ws_size,
                              hipStream_t stream) {
    const float* feat   = (const float*)d_in[0];
    const float* W      = (const float*)d_in[1];
    const float* attn_l = (const float*)d_in[2];
    const float* attn_r = (const float*)d_in[3];
    const int*   src    = (const int*)d_in[4];
    const int*   dst    = (const int*)d_in[5];
    float* out = (float*)d_out;

    const int M = in_sizes[0] / D_IN;   // 50000
    const int E = in_sizes[4];          // 800000
    const int nb = (M + 255) / 256;

    char* ws = (char*)d_ws;
    size_t o = 0;
    auto alloc = [&](size_t bytes) { size_t r = o; o = (o + bytes + 255) & ~(size_t)255; return r; };
    size_t off_projh = alloc((size_t)M * NOUT * 2);
    size_t off_el    = alloc((size_t)M * NH * 4);
    size_t off_er    = alloc((size_t)M * NH * 4);
    size_t off_deg   = alloc((size_t)M * 4);
    size_t off_ofs   = alloc((size_t)M * 4);
    size_t off_cur   = alloc((size_t)M * 4);
    size_t off_csr   = alloc((size_t)E * 4);
    size_t off_bsum  = alloc((size_t)nb * 4);
    size_t off_bth   = alloc((size_t)D_IN * NOUT * 2);
    size_t off_btl   = alloc((size_t)D_IN * NOUT * 2);
    size_t off_ahh   = alloc((size_t)M * D_IN * 2);
    size_t off_all   = alloc((size_t)M * D_IN * 2);

    unsigned short* projh = (unsigned short*)(ws + off_projh);
    float* el   = (float*)(ws + off_el);
    float* er   = (float*)(ws + off_er);
    int*   deg  = (int*)(ws + off_deg);
    int*   ofs  = (int*)(ws + off_ofs);
    int*   cur  = (int*)(ws + off_cur);
    int*   csr  = (int*)(ws + off_csr);
    int*   bsum = (int*)(ws + off_bsum);
    short* bth  = (short*)(ws + off_bth);
    short* btl  = (short*)(ws + off_btl);
    short* ahh  = (short*)(ws + off_ahh);
    short* allp = (short*)(ws + off_all);

    hipMemsetAsync(deg, 0, (size_t)M * 4, stream);

    // 1. A/W split + projection GEMM (split-bf16 MFMA, fused el/er epilogue)
    int total8 = M * D_IN / 8;
    asplit_kernel<<<(total8 + 255) / 256, 256, 0, stream>>>(feat, ahh, allp, total8);
    bsplit_kernel<<<NOUT, D_IN, 0, stream>>>(W, bth, btl);
    gemm_mfma_kernel<<<(M + 127) / 128, 256, 0, stream>>>(ahh, allp, bth, btl,
                                                          attn_l, attn_r,
                                                          (short*)projh, el, er, M);

    // 2. CSR build
    int eblocks = (E + 255) / 256;
    hist_kernel<<<eblocks, 256, 0, stream>>>(dst, deg, E);
    scan1_kernel<<<nb, 256, 0, stream>>>(deg, ofs, bsum, M);
    scan2_kernel<<<1, 256, 0, stream>>>(bsum, nb);
    scan3_kernel<<<nb, 256, 0, stream>>>(ofs, cur, bsum, M);
    scatter_kernel<<<eblocks, 256, 0, stream>>>(src, dst, cur, csr, E);

    // 3. fused softmax + aggregation (wave-per-dst, bf16 gather)
    agg_kernel<<<(M + 3) / 4, 256, 0, stream>>>(projh, el, er, csr, ofs, deg, out, M);
}